// Round 4
// baseline (175.992 us; speedup 1.0000x reference)
//
#include <hip/hip_runtime.h>

typedef __attribute__((ext_vector_type(8))) short short8;
typedef __attribute__((ext_vector_type(4))) float f32x4;

static __device__ __forceinline__ unsigned short f2b(float f) {
  union { float f; unsigned int u; } v; v.f = f;
  unsigned int u = v.u;
  unsigned int r = (u + 0x7FFFu + ((u >> 16) & 1u)) >> 16;
  return (unsigned short)r;
}
static __device__ __forceinline__ float b2f(unsigned short u) {
  union { unsigned int u; float f; } v; v.u = ((unsigned int)u) << 16;
  return v.f;
}

// ---------------------------------------------------------------------------
// K0: cast feature table (in_core | aux | zero row) and weight to bf16
// ---------------------------------------------------------------------------
__global__ __launch_bounds__(256) void prep_kernel(
    const float* __restrict__ core, const float* __restrict__ aux,
    const float* __restrict__ wgt,
    unsigned short* __restrict__ tab, unsigned short* __restrict__ wB)
{
  const long TAB = 12001L * 256;   // 3072256
  const long WN  = 256L * 2304;    // 589824
  long i = ((long)blockIdx.x * 256 + threadIdx.x) * 4;
  float4 v;
  unsigned short* dst;
  if (i < TAB) {
    long row = i >> 8;
    if (row < 8000)        v = *(const float4*)(core + i);
    else if (row < 12000)  v = *(const float4*)(aux + (i - 8000L * 256));
    else                   v = make_float4(0.f, 0.f, 0.f, 0.f);
    dst = tab + i;
  } else {
    long j = i - TAB;
    if (j >= WN) return;
    v = *(const float4*)(wgt + j);
    dst = wB + j;
  }
  ushort4 o = make_ushort4(f2b(v.x), f2b(v.y), f2b(v.z), f2b(v.w));
  *(ushort4*)dst = o;
}

// ---------------------------------------------------------------------------
// K1: projections (63 dots per row, f32) -> gids + combined weights
// block: 256 thr = 4 waves; wave handles 8 rows; grid 250
// NOTE reference's (non-standard) bilinear weights:
//   w[g] = delta[x_ids[g]] * (1-delta)[y_ids[g]], x_ids=[1,0,1,0], y_ids=[1,1,0,0]
//   -> factor1 = gx ? dx : dy ; factor2 = gy ? (1-dx) : (1-dy)
// ---------------------------------------------------------------------------
__global__ __launch_bounds__(256) void proj_kernel(
    const float* __restrict__ core,
    const float* __restrict__ off_w, const float* __restrict__ off_b,
    const float* __restrict__ pw_w,  const float* __restrict__ pw_b,
    const float* __restrict__ mw_w,  const float* __restrict__ mw_b,
    const int* __restrict__ id_map, const int* __restrict__ roi_ids,
    const int* __restrict__ pos_ids,
    int* __restrict__ gids, float* __restrict__ wts)
{
  __shared__ float dots[32][64];
  const int tid  = threadIdx.x;
  const int lane = tid & 63;
  const int wv   = tid >> 6;
  const int nbase = blockIdx.x * 32 + wv * 8;

  float acc[8] = {0.f,0.f,0.f,0.f,0.f,0.f,0.f,0.f};
  if (lane < 63) {
    const float* wr; float bb;
    if (lane < 36)      { wr = off_w + lane * 256;       bb = off_b[lane]; }
    else if (lane < 54) { wr = pw_w + (lane - 36) * 256; bb = pw_b[lane - 36]; }
    else                { wr = mw_w + (lane - 54) * 256; bb = mw_b[lane - 54]; }
    const float4* w4 = (const float4*)wr;
    #pragma unroll 4
    for (int i = 0; i < 64; ++i) {
      const float4 w = w4[i];
      #pragma unroll
      for (int r = 0; r < 8; ++r) {
        const float4 x = *(const float4*)(core + (long)(nbase + r) * 256 + i * 4);
        acc[r] += w.x * x.x + w.y * x.y + w.z * x.z + w.w * x.w;
      }
    }
    #pragma unroll
    for (int r = 0; r < 8; ++r) acc[r] += bb;
  }
  #pragma unroll
  for (int r = 0; r < 8; ++r) dots[wv * 8 + r][lane] = acc[r];
  __syncthreads();

  #pragma unroll
  for (int round = 0; round < 3; ++round) {
    int task = round * 256 + tid;
    if (task < 576) {
      int nl = task / 18;
      int kp = task - nl * 18;
      int k = kp >> 1, p = kp & 1;
      int n = blockIdx.x * 32 + nl;
      float x = dots[nl][k*4 + p*2 + 0] + (float)pos_ids[n*2 + 0];
      float y = dots[nl][k*4 + p*2 + 1] + (float)pos_ids[n*2 + 1];
      float fx = floorf(x), fy = floorf(y);
      float dx = x - fx, dy = y - fy;
      int bx = (int)fx, by = (int)fy;
      float l0 = dots[nl][36 + k*2], l1 = dots[nl][36 + k*2 + 1];
      float mmax = fmaxf(l0, l1);
      float e0 = __expf(l0 - mmax), e1 = __expf(l1 - mmax);
      float pwv = (p ? e1 : e0) / (e0 + e1);
      float mwv = 1.f / (1.f + __expf(-dots[nl][54 + k]));
      float wb  = pwv * mwv;
      const int* imap = id_map + roi_ids[n] * 4096;
      int base = ((n * 9 + k) * 2 + p) * 4;
      #pragma unroll
      for (int g = 0; g < 4; ++g) {
        int gx = g & 1, gy = g >> 1;
        int cx = bx + gx, cy = by + gy;
        bool pad = ((cx | cy) < 0) | (cx >= 64) | (cy >= 64);
        int cxc = min(max(cx, 0), 63), cyc = min(max(cy, 0), 63);
        int gid = pad ? 12000 : imap[cyc * 64 + cxc];
        // reference semantics (non-standard bilinear):
        float f1 = gx ? dx : dy;
        float f2 = gy ? (1.f - dx) : (1.f - dy);
        gids[base + g] = gid;
        wts[base + g]  = wb * f1 * f2;
      }
    }
  }
}

// ---------------------------------------------------------------------------
// K2: gather-combine -> sampled bf16 (8000 x 2304)
// block: 256 thr = 4 waves; wave per row n; lane owns 4 channels
// ---------------------------------------------------------------------------
__global__ __launch_bounds__(256) void gather_kernel(
    const unsigned short* __restrict__ tab,
    const int* __restrict__ gids, const float* __restrict__ wts,
    unsigned short* __restrict__ sampled)
{
  const int lane = threadIdx.x & 63;
  const int wv   = threadIdx.x >> 6;
  const int n    = blockIdx.x * 4 + wv;
  const int c    = lane * 4;
  #pragma unroll
  for (int k = 0; k < 9; ++k) {
    const int jb = (n * 9 + k) * 8;
    float a0 = 0.f, a1 = 0.f, a2 = 0.f, a3 = 0.f;
    #pragma unroll
    for (int j = 0; j < 8; ++j) {
      const int gid = gids[jb + j];
      const float w = wts[jb + j];
      const ushort4 t = *(const ushort4*)(tab + (long)gid * 256 + c);
      a0 += w * b2f(t.x); a1 += w * b2f(t.y);
      a2 += w * b2f(t.z); a3 += w * b2f(t.w);
    }
    ushort4 o = make_ushort4(f2b(a0), f2b(a1), f2b(a2), f2b(a3));
    *(ushort4*)(sampled + ((long)n * 2304 + k * 256 + c)) = o;
  }
}

// ---------------------------------------------------------------------------
// K3: out = sampled(8000x2304) @ weight^T(2304x256) + bias   (bf16 MFMA)
// 64x64 tile, BK=64, 4 waves (2x2), each wave 32x32 via 2x2 16x16x32 frags
// ---------------------------------------------------------------------------
__global__ __launch_bounds__(256) void gemm_kernel(
    const unsigned short* __restrict__ S,
    const unsigned short* __restrict__ W,
    const float* __restrict__ bias,
    float* __restrict__ out)
{
  __shared__ __align__(16) unsigned short As[64][72];
  __shared__ __align__(16) unsigned short Bs[64][72];
  const int m0 = blockIdx.x * 64;
  const int n0 = blockIdx.y * 64;
  const int t    = threadIdx.x;
  const int lane = t & 63;
  const int wv   = t >> 6;
  const int wr   = wv >> 1, wc = wv & 1;

  f32x4 acc[2][2] = {};

  const int srow = t >> 3;   // 0..31
  const int schk = t & 7;    // 0..7

  for (int kt = 0; kt < 36; ++kt) {
    const int k0 = kt * 64;
    const uint4 ra0 = *(const uint4*)(S + (long)(m0 + srow)      * 2304 + k0 + schk * 8);
    const uint4 ra1 = *(const uint4*)(S + (long)(m0 + srow + 32) * 2304 + k0 + schk * 8);
    const uint4 rb0 = *(const uint4*)(W + (long)(n0 + srow)      * 2304 + k0 + schk * 8);
    const uint4 rb1 = *(const uint4*)(W + (long)(n0 + srow + 32) * 2304 + k0 + schk * 8);
    __syncthreads();
    *(uint4*)&As[srow][schk * 8]      = ra0;
    *(uint4*)&As[srow + 32][schk * 8] = ra1;
    *(uint4*)&Bs[srow][schk * 8]      = rb0;
    *(uint4*)&Bs[srow + 32][schk * 8] = rb1;
    __syncthreads();
    #pragma unroll
    for (int kc = 0; kc < 2; ++kc) {
      const int kk = kc * 32 + (lane >> 4) * 8;
      short8 af[2], bf[2];
      af[0] = *(const short8*)&As[wr * 32 + (lane & 15)][kk];
      af[1] = *(const short8*)&As[wr * 32 + 16 + (lane & 15)][kk];
      bf[0] = *(const short8*)&Bs[wc * 32 + (lane & 15)][kk];
      bf[1] = *(const short8*)&Bs[wc * 32 + 16 + (lane & 15)][kk];
      #pragma unroll
      for (int i = 0; i < 2; ++i)
        #pragma unroll
        for (int j = 0; j < 2; ++j)
          acc[i][j] = __builtin_amdgcn_mfma_f32_16x16x32_bf16(af[i], bf[j], acc[i][j], 0, 0, 0);
    }
  }

  #pragma unroll
  for (int i = 0; i < 2; ++i) {
    const int row = m0 + wr * 32 + i * 16 + (lane >> 4) * 4;
    #pragma unroll
    for (int j = 0; j < 2; ++j) {
      const int col = n0 + wc * 32 + j * 16 + (lane & 15);
      const float bs = bias[col];
      #pragma unroll
      for (int r = 0; r < 4; ++r) {
        out[(long)(row + r) * 256 + col] = acc[i][j][r] + bs;
      }
    }
  }
}

// ---------------------------------------------------------------------------
extern "C" void kernel_launch(void* const* d_in, const int* in_sizes, int n_in,
                              void* d_out, int out_size, void* d_ws, size_t ws_size,
                              hipStream_t stream)
{
  const float* core   = (const float*)d_in[0];
  const float* aux    = (const float*)d_in[1];
  const float* off_w  = (const float*)d_in[2];
  const float* off_b  = (const float*)d_in[3];
  const float* pw_w   = (const float*)d_in[4];
  const float* pw_b   = (const float*)d_in[5];
  const float* mw_w   = (const float*)d_in[6];
  const float* mw_b   = (const float*)d_in[7];
  const float* wgt    = (const float*)d_in[8];
  const float* bias   = (const float*)d_in[9];
  const int* id_map   = (const int*)d_in[10];
  const int* roi_ids  = (const int*)d_in[11];
  const int* pos_ids  = (const int*)d_in[12];
  char* ws = (char*)d_ws;

  unsigned short* tab     = (unsigned short*)(ws);              // 12001*256*2 = 6,144,512
  unsigned short* wB      = (unsigned short*)(ws + 6144512);    // 256*2304*2  = 1,179,648
  int*            gids    = (int*)           (ws + 7324160);    // 8000*72*4   = 2,304,000
  float*          wts     = (float*)         (ws + 9628160);    // 8000*72*4   = 2,304,000
  unsigned short* sampled = (unsigned short*)(ws + 11932160);   // 8000*2304*2 = 36,864,000
  float* out = (float*)d_out;

  hipLaunchKernelGGL(prep_kernel, dim3(3577), dim3(256), 0, stream,
                     core, aux, wgt, tab, wB);
  hipLaunchKernelGGL(proj_kernel, dim3(250), dim3(256), 0, stream,
                     core, off_w, off_b, pw_w, pw_b, mw_w, mw_b,
                     id_map, roi_ids, pos_ids, gids, wts);
  hipLaunchKernelGGL(gather_kernel, dim3(2000), dim3(256), 0, stream,
                     tab, gids, wts, sampled);
  hipLaunchKernelGGL(gemm_kernel, dim3(125, 4), dim3(256), 0, stream,
                     sampled, wB, bias, out);
}